// Round 10
// baseline (110.453 us; speedup 1.0000x reference)
//
#include <hip/hip_runtime.h>
#include <math.h>

#define Bn 8
#define Qn 20
#define Pn 12
#define Nn 4096
#define Gn 2048
#define Mn 1280   /* Q*FACTOR */
#define Fn 64
#define KNB 7     /* K_NEIGHBORS - 1 */
#define NCOST 160
#define NCHA 160  /* chamfer A blocks: outer recon chunks of 64 */
#define NCHB 256  /* chamfer B blocks: outer gt chunks of 64 */
#define NREP 20   /* 8 groups per block */
#define NBLK1 596 /* 160 + 160 + 256 + 20 */

// ---------------- workspace layout (32-bit words) ----------------
// cham  : 0     (1920)   ns: 1920  dd: 3840  cost: 5760  cnt: 7680
// slotA : 8192  (320)  {c1,c2} per A chunk (dense -- plain stores now)
// slotB : 8512  (512)  {c1,c2} per B chunk
// rep   : 9024  (160)  per-group repulsion partials
//
// R16: two dispatches, ZERO atomics/spins/uncached ops. Evidence: every
// single-dispatch variant (R10/12/13/14/15) lands 42-55us regardless of
// structure -- the common factor is device-scope uncached transport + gating
// chains (~900cy/hop) on the critical path. R9 showed a kernel boundary
// costs only ~5-10us and gives free coherence for plain L2 stores. So:
//   K1 (596 blks): cost + 416-spread chamfer (in-block finish -> plain slot
//       stores, counters deleted) + rep partials. All plain memory.
//   K2 (ONE block): 8 JVs, one per WAVE (JV is wave-synchronous:
//       readlane/DPP/shfl all wave-local) -> no cross-block gate exists;
//       then parallel slot gather -> LDS, exact rep tree, canonical sum.
// All values + summation orders bitwise == the absmax-0.0 lineage.

__device__ __forceinline__ int rdlane_i(int v, int l) {
    return __builtin_amdgcn_readlane(v, l);
}
__device__ __forceinline__ float rdlane_f(float v, int l) {
    return __int_as_float(__builtin_amdgcn_readlane(__float_as_int(v), l));
}
// full-wave min via DPP (VALU pipe); result valid in lane 63.
__device__ __forceinline__ unsigned wave_min_u32(unsigned x) {
    unsigned t;
    t = (unsigned)__builtin_amdgcn_update_dpp((int)0xFFFFFFFF, (int)x, 0x111, 0xF, 0xF, false);
    x = t < x ? t : x;
    t = (unsigned)__builtin_amdgcn_update_dpp((int)0xFFFFFFFF, (int)x, 0x112, 0xF, 0xF, false);
    x = t < x ? t : x;
    t = (unsigned)__builtin_amdgcn_update_dpp((int)0xFFFFFFFF, (int)x, 0x114, 0xF, 0xF, false);
    x = t < x ? t : x;
    t = (unsigned)__builtin_amdgcn_update_dpp((int)0xFFFFFFFF, (int)x, 0x118, 0xF, 0xF, false);
    x = t < x ? t : x;
    t = (unsigned)__builtin_amdgcn_update_dpp((int)0xFFFFFFFF, (int)x, 0x142, 0xF, 0xF, false);
    x = t < x ? t : x;
    t = (unsigned)__builtin_amdgcn_update_dpp((int)0xFFFFFFFF, (int)x, 0x143, 0xF, 0xF, false);
    x = t < x ? t : x;
    return x;
}

// ============ K1: cost (160) + chamfer (416) + rep partials (20) ============
__global__ __launch_bounds__(512, 2)
void k1_kernel(const float* __restrict__ pred_normals,
               const float* __restrict__ pred_distances,
               const float* __restrict__ gt_normals,
               const float* __restrict__ gt_distances,
               const float* __restrict__ points,
               const int*   __restrict__ gt_masks,
               const float* __restrict__ recon,
               const float* __restrict__ gt,
               float* __restrict__ ws) {
    __shared__ __align__(16) float smem[8192];   // 32 KB
    const int blk = blockIdx.x;
    const int tid = threadIdx.x;

    float* cham = ws;
    float* ns   = ws + 1920;
    float* dd   = ws + 3840;
    float* cost = ws + 5760;
    float* cnt  = ws + 7680;
    float* slotA = ws + 8192;
    float* slotB = ws + 8512;
    float* rep_part = ws + 9024;

    if (blk < NCOST) {
        // ================= cost path (bitwise == R15; XCD-swizzled) =========
        const int b = blk & 7, q = blk >> 3;
        const float nx = pred_normals[(b * Qn + q) * 3 + 0];
        const float ny = pred_normals[(b * Qn + q) * 3 + 1];
        const float nz = pred_normals[(b * Qn + q) * 3 + 2];
        const float dq = pred_distances[b * Qn + q];

        if (tid < 256) {
            float accs[Pn], accw[Pn];
#pragma unroll
            for (int p = 0; p < Pn; ++p) { accs[p] = 0.f; accw[p] = 0.f; }
            const float* ptb = points + (size_t)b * Nn * 3;
            const int*   mb  = gt_masks + (size_t)b * Pn * Nn;
            for (int n = tid; n < Nn; n += 256) {
                float px = ptb[n * 3 + 0], py = ptb[n * 3 + 1], pz = ptb[n * 3 + 2];
                float pp = fabsf(px * nx + py * ny + pz * nz - dq);
#pragma unroll
                for (int p = 0; p < Pn; ++p) {
                    float m = (float)mb[(size_t)p * Nn + n];
                    accs[p] += pp * m;
                    accw[p] += m;
                }
            }
#pragma unroll
            for (int p = 0; p < Pn; ++p) {
                smem[p * 256 + tid] = accs[p];
                smem[(p + Pn) * 256 + tid] = accw[p];
            }
        }
        __syncthreads();
        for (int off = 128; off > 0; off >>= 1) {
            if (tid < off) {
#pragma unroll
                for (int r = 0; r < 2 * Pn; ++r) smem[r * 256 + tid] += smem[r * 256 + tid + off];
            }
            __syncthreads();
        }
        if (tid < Pn) {
            const int p = tid;
            float c  = smem[(p + Pn) * 256];
            float cv = smem[p * 256] / fmaxf(c, 1.f);
            float gnx = gt_normals[(b * Pn + p) * 3 + 0];
            float gny = gt_normals[(b * Pn + p) * 3 + 1];
            float gnz = gt_normals[(b * Pn + p) * 3 + 2];
            float nsim = 1.f - fabsf(nx * gnx + ny * gny + nz * gnz);
            float ddv  = fabsf(dq - gt_distances[b * Pn + p]);
            int idx = (b * Qn + q) * Pn + p;
            cham[idx] = cv;
            ns[idx]   = nsim;
            dd[idx]   = ddv;
            cost[idx] = nsim + 0.5f * ddv + 5.f * ((c > 0.f) ? cv : 1.f);
            if (q == 0) cnt[b * Pn + p] = c;
        }
        return;
    } else if (blk < NCOST + NCHA + NCHB) {
        // ============ chamfer: inner cloud in LDS, 8-way intra-block split ==========
        const int a0 = blk - NCOST;
        const bool isA = (a0 < NCHA);
        int chunk;
        if (isA) { int r = a0;        chunk = (r & 7) * 20 + (r >> 3); }
        else     { int r = a0 - NCHA; chunk = (r & 7) * 32 + (r >> 3); }
        const int lt = tid & 63;
        const int part = tid >> 6;           // 0..7
        const int idx = chunk * 64 + lt;
        const float* inner;
        const float* op;
        int ninner;
        float scale;
        float* slot;
        if (isA) {
            const int b = idx / Mn;          // outer = recon, inner = gt[b] (2048)
            inner = gt + (size_t)b * Gn * 3;
            op = recon + (size_t)idx * 3;
            ninner = Gn;
            scale = 0.5f / (float)(Bn * Mn);
            slot = slotA + 2 * chunk;
        } else {
            const int b = idx / Gn;          // outer = gt, inner = recon[b] (1280)
            inner = recon + (size_t)b * Mn * 3;
            op = gt + (size_t)idx * 3;
            ninner = Mn;
            scale = 0.5f / (float)(Bn * Gn);
            slot = slotB + 2 * chunk;
        }
        float4* tile = reinterpret_cast<float4*>(smem);
        for (int j = tid; j < ninner; j += 512) {
            const float* ip = inner + j * 3;
            float4 tv;
            tv.x = ip[0]; tv.y = ip[1]; tv.z = ip[2]; tv.w = 0.f;
            tile[j] = tv;
        }
        __syncthreads();
        const float x = op[0], y = op[1], z = op[2];
        const int span = ninner >> 3;        // 256 (A) or 160 (B)
        const int j0 = part * span, j1 = j0 + span;
        float m1 = 3.4e38f, m2 = 3.4e38f;
#pragma unroll 4
        for (int j = j0; j < j1; ++j) {
            float4 tv = tile[j];
            float dx = x - tv.x, dy = y - tv.y, dz = z - tv.z;
            float d1 = fabsf(dx) + fabsf(dy) + fabsf(dz);
            float d2 = dx * dx + dy * dy + dz * dz;
            m1 = fminf(m1, d1); m2 = fminf(m2, d2);
        }
        __syncthreads();                     // tile dead; reuse smem
        float* s1 = smem;
        float* s2 = smem + 512;
        s1[tid] = m1;
        s2[tid] = m2;
        __syncthreads();
        float* t1 = smem + 1024;
        float* t2 = smem + 1088;
        if (tid < 64) {
            float M1 = s1[tid], M2 = s2[tid];
#pragma unroll
            for (int pp = 1; pp < 8; ++pp) {     // min: order-exact
                M1 = fminf(M1, s1[pp * 64 + tid]);
                M2 = fminf(M2, s2[pp * 64 + tid]);
            }
            t1[tid] = M1 * scale;
            t2[tid] = M2 * scale;
        }
        __syncthreads();
        for (int off = 32; off > 0; off >>= 1) {
            if (tid < off) { t1[tid] += t1[tid + off]; t2[tid] += t2[tid + off]; }
            __syncthreads();
        }
        if (tid == 0) {
            slot[0] = t1[0];
            slot[1] = t2[0];
        }
        return;
    }

    // ================= repulsion partials: 8 waves/block, 20 blocks =========
    {
        const int wave = tid >> 6, lane = tid & 63;
        const int g = (blk - (NCOST + NCHA + NCHB)) * 8 + wave;
        float* xs = smem + wave * 192;
        float* ys = xs + 64;
        float* zs = xs + 128;
        const float* base = recon + (size_t)g * Fn * 3;
        xs[lane] = base[lane * 3 + 0];
        ys[lane] = base[lane * 3 + 1];
        zs[lane] = base[lane * 3 + 2];
        float best[KNB];
#pragma unroll
        for (int k = 0; k < KNB; ++k) best[k] = 3.4e38f;
        const float xi = xs[lane], yi = ys[lane], zi = zs[lane];
        for (int j = 0; j < Fn; ++j) {
            float dx = xi - xs[j], dy = yi - ys[j], dz = zi - zs[j];
            float d2 = dx * dx + dy * dy + dz * dz;
            d2 = (j == lane) ? 3.4e38f : d2;
#pragma unroll
            for (int k = 0; k < KNB; ++k) {
                float lo = fminf(best[k], d2);
                float hi = fmaxf(best[k], d2);
                best[k] = lo;
                d2 = hi;
            }
        }
        float sum = 0.f;
#pragma unroll
        for (int k = 0; k < KNB; ++k) {
            float dn = fmaxf(best[k], 1e-12f);
            float w  = expf(-dn / (0.03f * 0.03f));
            sum += (0.07f - sqrtf(dn)) * w;
        }
        for (int off = 32; off > 0; off >>= 1) sum += __shfl_down(sum, off);
        if (lane == 0) rep_part[g] = fmaxf(sum / (float)(Fn * KNB), 0.f);
    }
}

// ============ K2: ONE block -- 8 JVs (one per wave) + gather + final sum ============
__global__ void k2_kernel(const float* __restrict__ pred_logits,
                          const float* __restrict__ ws,
                          float* __restrict__ out) {
    __shared__ float sjv[24];     // {cls,par,pvd} per batch
    __shared__ float sA[320];
    __shared__ float sB[512];
    __shared__ float sR[256];
    const int tid = threadIdx.x;
    const int t = tid & 63;       // col within wave
    const int b2 = tid >> 6;      // batch == wave id

    const float* cham = ws;
    const float* ns   = ws + 1920;
    const float* dd   = ws + 3840;
    const float* cost = ws + 5760;
    const float* cnt  = ws + 7680;
    const float* slotA = ws + 8192;
    const float* slotB = ws + 8512;
    const float* rep_part = ws + 9024;

    // ---- per-wave transposed rectangular JV (R15 body, plain loads) ----
    {
        const int col = t;
        const bool isCol = (col >= 1 && col <= Qn);

        float cr[Pn];
#pragma unroll
        for (int k = 0; k < Pn; ++k) cr[k] = 0.f;
        if (isCol) {
            const float* cb = cost + ((size_t)b2 * Qn + (col - 1)) * Pn;
#pragma unroll
            for (int k = 0; k < Pn; ++k) cr[k] = cb[k];
        }

        float v = 0.f, u = 0.f, minv = 0.f;
        int way = 0, p = 0;

        for (int i = 1; i <= Pn; ++i) {
            minv = 1e30f;
            bool used = false;
            bool rowInPath = false;
            int j0s = 0;
            while (true) {
                if (col == j0s) used = true;
                int i0s = (j0s == 0) ? i : rdlane_i(p, j0s);
                if (t == i0s) rowInPath = true;
                float u_i0 = rdlane_f(u, i0s);
                const int bs = i0s - 1;
                float l10 = (bs & 1) ? cr[1]  : cr[0];
                float l11 = (bs & 1) ? cr[3]  : cr[2];
                float l12 = (bs & 1) ? cr[5]  : cr[4];
                float l13 = (bs & 1) ? cr[7]  : cr[6];
                float l14 = (bs & 1) ? cr[9]  : cr[8];
                float l15 = (bs & 1) ? cr[11] : cr[10];
                float l20 = (bs & 2) ? l11 : l10;
                float l21 = (bs & 2) ? l13 : l12;
                float l22 = (bs & 2) ? l15 : l14;
                float cij = (bs >= 8) ? l22 : ((bs >= 4) ? l21 : l20);
                if (isCol && !used) {
                    float cur = cij - u_i0 - v;
                    if (cur < minv) { minv = cur; way = j0s; }
                }
                float mv = (isCol && !used) ? minv : 1e30f;
                unsigned kb = __float_as_uint(mv);
                kb = ((int)kb < 0) ? ~kb : (kb | 0x80000000u);
                kb = (kb & ~31u) | (unsigned)(col & 31);
                unsigned kmin = (unsigned)rdlane_i((int)wave_min_u32(kb), 63);
                int j1 = (int)(kmin & 31u);
                float delta = rdlane_f(minv, j1);
                if (used || col == 0) v -= delta;
                else if (isCol)       minv -= delta;
                if (rowInPath)        u += delta;
                j0s = j1;
                int pj0 = rdlane_i(p, j0s);
                if (pj0 == 0) break;
            }
            while (j0s != 0) {
                int wj = rdlane_i(way, j0s);
                int pw = (wj == 0) ? i : rdlane_i(p, wj);
                if (col == j0s) p = pw;
                j0s = wj;
            }
        }

        float cls = 0.f, par = 0.f, pvd = 0.f;
        if (isCol) {
            float x = pred_logits[b2 * Qn + (col - 1)];
            float tgt = (p > 0) ? 1.f : 0.f;
            cls = fmaxf(x, 0.f) - x * tgt + log1pf(expf(-fabsf(x)));
            if (p > 0) {
                int idx = (b2 * Qn + (col - 1)) * Pn + (p - 1);
                par = ns[idx] + dd[idx];
                pvd = (cnt[b2 * Pn + (p - 1)] > 0.f) ? cham[idx] : 0.f;
            }
        }
        for (int off = 32; off > 0; off >>= 1) {
            cls += __shfl_down(cls, off);
            par += __shfl_down(par, off);
            pvd += __shfl_down(pvd, off);
        }
        if (t == 0) {
            sjv[3 * b2 + 0] = cls / (float)(Bn * Qn);
            sjv[3 * b2 + 1] = par / (float)(Bn * Pn);
            sjv[3 * b2 + 2] = pvd / (float)(Bn * Pn);
        }
    }

    // ---- parallel slot gather + exact rep tree ----
    if (tid < 320) sA[tid] = slotA[tid];
    if (tid < 512) sB[tid] = slotB[tid];
    if (tid < 256) sR[tid] = (tid < Bn * Qn) ? rep_part[tid] / (float)(Bn * Qn) : 0.f;
    __syncthreads();
    for (int off = 128; off > 0; off >>= 1) {
        if (tid < off) sR[tid] += sR[tid + off];
        __syncthreads();
    }

    // ---- canonical-order final sum (bitwise == R15 assemble) ----
    if (tid == 0) {
        float a0 = 0.f, a1 = 0.f, a2 = 0.f, a4 = 0.f, a5 = 0.f;
#pragma unroll
        for (int b = 0; b < 8; ++b) {
            a0 += sjv[3 * b + 0];
            a1 += sjv[3 * b + 1];
            a2 += sjv[3 * b + 2];
        }
#pragma unroll 8
        for (int c = 0; c < NCHA; ++c) {
            a4 += sA[2 * c + 0];
            a5 += sA[2 * c + 1];
        }
#pragma unroll 8
        for (int c = 0; c < NCHB; ++c) {
            a4 += sB[2 * c + 0];
            a5 += sB[2 * c + 1];
        }
        float a3 = sR[0];
        out[0] = a0 + 0.5f * a1 + 20.f * a2 + a3 + a4 + a5;
    }
}

extern "C" void kernel_launch(void* const* d_in, const int* in_sizes, int n_in,
                              void* d_out, int out_size, void* d_ws, size_t ws_size,
                              hipStream_t stream) {
    const float* pred_logits    = (const float*)d_in[0];
    const float* pred_normals   = (const float*)d_in[1];
    const float* pred_distances = (const float*)d_in[2];
    const float* gt_normals     = (const float*)d_in[3];
    const float* gt_distances   = (const float*)d_in[4];
    const int*   gt_masks       = (const int*)d_in[5];
    const float* points         = (const float*)d_in[6];
    const float* recon          = (const float*)d_in[7];
    const float* gt             = (const float*)d_in[8];
    // d_in[9] (gt_index) is unused by the reference.

    k1_kernel<<<NBLK1, 512, 0, stream>>>(pred_normals, pred_distances, gt_normals,
                                         gt_distances, points, gt_masks, recon, gt,
                                         (float*)d_ws);
    k2_kernel<<<1, 512, 0, stream>>>(pred_logits, (const float*)d_ws, (float*)d_out);
}